// Round 4
// baseline (9257.377 us; speedup 1.0000x reference)
//
#include <hip/hip_runtime.h>

#define LAYERS    5
#define INPUT_DIM 512
#define CODE_DIM  2048
#define BATCH     32768
#define KSP       32

#define BM  128
#define BN  128
#define BKT 16

// ---------------------------------------------------------------------------
// D [512][2048] -> Dt [2048][512]  (bit copy, no arithmetic)
__global__ __launch_bounds__(256) void transpose_512x2048_kernel(const float* __restrict__ src,
                                                                 float* __restrict__ dst)
{
    __shared__ float tile[32][33];
    const int tx = threadIdx.x;
    const int ty = threadIdx.y;
    const int cb = blockIdx.x * 32;
    const int ib = blockIdx.y * 32;
    #pragma unroll
    for (int j = 0; j < 32; j += 8)
        tile[ty + j][tx] = src[(size_t)(ib + ty + j) * CODE_DIM + cb + tx];
    __syncthreads();
    #pragma unroll
    for (int j = 0; j < 32; j += 8)
        dst[(size_t)(cb + ty + j) * INPUT_DIM + ib + tx] = tile[tx][ty + j];
}

// ---------------------------------------------------------------------------
// u = x@Wl  (+ z@Sl for l>0), faithful to np/BLAS f32 semantics:
//  - x@W: per output, ONE f32 accumulator, k = 0..511 strictly ascending, fmaf
//  - z@S: SEPARATE zero-init accumulator, 32 nonzeros folded in ascending
//         code-index order (zidx/zval arrive index-sorted), fmaf
//  - u = xw + zs: one final add
__global__ __launch_bounds__(256) void gemm_layer_kernel(
    const float* __restrict__ x, const float* __restrict__ Wl,
    const float* __restrict__ Sl, const int* __restrict__ zidx,
    const float* __restrict__ zval, float* __restrict__ u)
{
    __shared__ float As[BKT][BM + 4];   // As[k][m]
    __shared__ float Bs[BKT][BN + 4];

    const int t   = threadIdx.x;
    const int c0  = blockIdx.x * BN;
    const int r0  = blockIdx.y * BM;
    const int tm0 = (t >> 4) * 8;
    const int tn0 = (t & 15) * 8;

    float acc[8][8];
    #pragma unroll
    for (int i = 0; i < 8; ++i)
        #pragma unroll
        for (int j = 0; j < 8; ++j) acc[i][j] = 0.f;

    for (int kt = 0; kt < INPUT_DIM; kt += BKT) {
        #pragma unroll
        for (int i = 0; i < 2; ++i) {
            int f   = t * 2 + i;
            int row = f >> 2, kq = f & 3;
            float4 v = *(const float4*)&x[(size_t)(r0 + row) * INPUT_DIM + kt + kq * 4];
            As[kq * 4 + 0][row] = v.x;
            As[kq * 4 + 1][row] = v.y;
            As[kq * 4 + 2][row] = v.z;
            As[kq * 4 + 3][row] = v.w;
        }
        #pragma unroll
        for (int i = 0; i < 2; ++i) {
            int g  = t * 2 + i;
            int kr = g >> 5, cq = g & 31;
            *(float4*)&Bs[kr][cq * 4] =
                *(const float4*)&Wl[(size_t)(kt + kr) * CODE_DIM + c0 + cq * 4];
        }
        __syncthreads();
        #pragma unroll
        for (int kk = 0; kk < BKT; ++kk) {      // strictly ascending k chain
            float a[8], b[8];
            *(float4*)&a[0] = *(const float4*)&As[kk][tm0];
            *(float4*)&a[4] = *(const float4*)&As[kk][tm0 + 4];
            *(float4*)&b[0] = *(const float4*)&Bs[kk][tn0];
            *(float4*)&b[4] = *(const float4*)&Bs[kk][tn0 + 4];
            #pragma unroll
            for (int i = 0; i < 8; ++i)
                #pragma unroll
                for (int j = 0; j < 8; ++j)
                    acc[i][j] = fmaf(a[i], b[j], acc[i][j]);
        }
        __syncthreads();
    }

    if (Sl != nullptr) {
        #pragma unroll
        for (int i = 0; i < 8; ++i) {
            const int r = r0 + tm0 + i;
            const int*   ip = zidx + (size_t)r * KSP;   // index-sorted ascending
            const float* vp = zval + (size_t)r * KSP;
            float zacc[8];
            #pragma unroll
            for (int j = 0; j < 8; ++j) zacc[j] = 0.f;
            for (int k = 0; k < KSP; ++k) {             // ascending code index
                int   j = ip[k];
                float v = vp[k];
                const float* srow = Sl + (size_t)j * CODE_DIM + c0 + tn0;
                float4 s0 = *(const float4*)&srow[0];
                float4 s1 = *(const float4*)&srow[4];
                zacc[0] = fmaf(v, s0.x, zacc[0]);
                zacc[1] = fmaf(v, s0.y, zacc[1]);
                zacc[2] = fmaf(v, s0.z, zacc[2]);
                zacc[3] = fmaf(v, s0.w, zacc[3]);
                zacc[4] = fmaf(v, s1.x, zacc[4]);
                zacc[5] = fmaf(v, s1.y, zacc[5]);
                zacc[6] = fmaf(v, s1.z, zacc[6]);
                zacc[7] = fmaf(v, s1.w, zacc[7]);
            }
            #pragma unroll
            for (int j = 0; j < 8; ++j)                 // single add, like xw + zs
                acc[i][j] = acc[i][j] + zacc[j];
        }
    }

    #pragma unroll
    for (int i = 0; i < 8; ++i) {
        float* up = u + (size_t)(r0 + tm0 + i) * CODE_DIM + c0 + tn0;
        *(float4*)&up[0] = make_float4(acc[i][0], acc[i][1], acc[i][2], acc[i][3]);
        *(float4*)&up[4] = make_float4(acc[i][4], acc[i][5], acc[i][6], acc[i][7]);
    }
}

// ---------------------------------------------------------------------------
// per-row top-32 by |u| (desc, tie -> lower index), output sorted by INDEX
__global__ __launch_bounds__(256) void topk32_kernel(const float* __restrict__ u,
                                                     int* __restrict__ zidx,
                                                     float* __restrict__ zval)
{
    __shared__ float a[CODE_DIM];
    __shared__ float rv[4];
    __shared__ int   ri[4];
    __shared__ int   sel_i[KSP];
    __shared__ float sel_v[KSP];
    const int t    = threadIdx.x;
    const int row  = blockIdx.x;
    const int lane = t & 63, wid = t >> 6;
    const float* ur = u + (size_t)row * CODE_DIM;

    for (int i = t; i < CODE_DIM; i += 256) a[i] = fabsf(ur[i]);
    __syncthreads();

    for (int it = 0; it < KSP; ++it) {
        float best = -1.f;
        int   bi   = 0x7fffffff;
        for (int i = t; i < CODE_DIM; i += 256) {
            float v = a[i];
            if (v > best) { best = v; bi = i; }          // keeps lowest i on ties
        }
        #pragma unroll
        for (int off = 32; off >= 1; off >>= 1) {
            float ov = __shfl_down(best, off);
            int   oi = __shfl_down(bi, off);
            if (ov > best || (ov == best && oi < bi)) { best = ov; bi = oi; }
        }
        if (lane == 0) { rv[wid] = best; ri[wid] = bi; }
        __syncthreads();
        if (t == 0) {
            #pragma unroll
            for (int w = 1; w < 4; ++w) {
                float ov = rv[w]; int oi = ri[w];
                if (ov > best || (ov == best && oi < bi)) { best = ov; bi = oi; }
            }
            sel_i[it] = bi;
            sel_v[it] = ur[bi];
            a[bi] = -1.f;
        }
        __syncthreads();
    }

    // write index-sorted (rank by index; all indices distinct)
    if (t < KSP) {
        int   mi = sel_i[t];
        float mv = sel_v[t];
        int rank = 0;
        #pragma unroll
        for (int m = 0; m < KSP; ++m) rank += (sel_i[m] < mi) ? 1 : 0;
        zidx[(size_t)row * KSP + rank] = mi;
        zval[(size_t)row * KSP + rank] = mv;
    }
}

// ---------------------------------------------------------------------------
__global__ __launch_bounds__(256) void zfill_scatter_kernel(const int* __restrict__ zidx,
                                                            const float* __restrict__ zval,
                                                            float* __restrict__ zden)
{
    const int t  = threadIdx.x;
    const int r0 = blockIdx.x * 8;
    float* base = zden + (size_t)r0 * CODE_DIM;
    const float4 zero = make_float4(0.f, 0.f, 0.f, 0.f);
    for (int q = t; q < 8 * CODE_DIM / 4; q += 256)
        *(float4*)&base[q * 4] = zero;
    __syncthreads();
    const int rl = t >> 5, k = t & 31;
    int   idx = zidx[(size_t)(r0 + rl) * KSP + k];
    float v   = zval[(size_t)(r0 + rl) * KSP + k];
    base[(size_t)rl * CODE_DIM + idx] = v;
}

// ---------------------------------------------------------------------------
// recon[r][i] = fold over the 32 (idx-sorted) nonzeros, ascending, f32 fmaf —
// bitwise equal to np's z @ D.T k-chain (zero terms are exact no-ops)
__global__ __launch_bounds__(128) void recon_kernel(const int* __restrict__ zidx,
                                                    const float* __restrict__ zval,
                                                    const float* __restrict__ Dt,
                                                    float* __restrict__ recon)
{
    const int t   = threadIdx.x;   // 0..127 -> 512 cols as float4
    const int row = blockIdx.x;
    float4 acc = make_float4(0.f, 0.f, 0.f, 0.f);
    const int*   ip = zidx + (size_t)row * KSP;
    const float* vp = zval + (size_t)row * KSP;
    for (int k = 0; k < KSP; ++k) {            // ascending index order
        int   j = ip[k];
        float v = vp[k];
        float4 d = *(const float4*)&Dt[(size_t)j * INPUT_DIM + t * 4];
        acc.x = fmaf(v, d.x, acc.x);
        acc.y = fmaf(v, d.y, acc.y);
        acc.z = fmaf(v, d.z, acc.z);
        acc.w = fmaf(v, d.w, acc.w);
    }
    *(float4*)&recon[(size_t)row * INPUT_DIM + t * 4] = acc;
}

// ---------------------------------------------------------------------------
extern "C" void kernel_launch(void* const* d_in, const int* in_sizes, int n_in,
                              void* d_out, int out_size, void* d_ws, size_t ws_size,
                              hipStream_t stream)
{
    const float* x = (const float*)d_in[0];
    const float* W = (const float*)d_in[1];   // [5][512][2048]
    const float* S = (const float*)d_in[2];   // [5][2048][2048]
    const float* D = (const float*)d_in[3];   // [512][2048]

    float* recon = (float*)d_out;
    float* zden  = (float*)d_out + (size_t)BATCH * INPUT_DIM;  // u scratch, then final dense z

    int*   zidx = (int*)d_ws;                                       // 4 MB
    float* zval = (float*)((char*)d_ws + (size_t)BATCH * KSP * 4);  // 4 MB
    float* Dt   = (float*)((char*)d_ws + (size_t)2 * BATCH * KSP * 4); // 4 MB

    transpose_512x2048_kernel<<<dim3(CODE_DIM / 32, INPUT_DIM / 32), dim3(32, 8), 0, stream>>>(D, Dt);

    for (int l = 0; l < LAYERS; ++l) {
        const float* Wl = W + (size_t)l * INPUT_DIM * CODE_DIM;
        const float* Sl = (l == 0) ? nullptr : S + (size_t)l * CODE_DIM * CODE_DIM;
        gemm_layer_kernel<<<dim3(CODE_DIM / BN, BATCH / BM), 256, 0, stream>>>(
            x, Wl, Sl, (l == 0) ? nullptr : zidx, (l == 0) ? nullptr : zval, zden);
        topk32_kernel<<<BATCH, 256, 0, stream>>>(zden, zidx, zval);
    }

    zfill_scatter_kernel<<<BATCH / 8, 256, 0, stream>>>(zidx, zval, zden);
    recon_kernel<<<BATCH, 128, 0, stream>>>(zidx, zval, Dt, recon);
}